// Round 1
// baseline (40.334 us; speedup 1.0000x reference)
//
#include <hip/hip_runtime.h>
#include <math.h>

// SSKernelDiag: out[c=0,h,l] = 2*Re( sum_n C'[h,n] * A[h,n]^l )
//   A  = exp(al + i*ph)            (al=A_abslog, ph=A_phase)
//   C' = (C0 + i*C1) * (A-1)/(al + i*ph)
// H=256, N=64, L=4096, CH=1.

constexpr int H = 256;
constexpr int N = 64;
constexpr int L = 4096;

constexpr int SPLIT  = 2;            // l-range splits per head
constexpr int BLK    = 256;
constexpr int LCHUNK = L / SPLIT;    // 2048
constexpr int LPT    = LCHUNK / BLK; // 8 consecutive l per thread

__global__ __launch_bounds__(BLK)
void sskdiag_kernel(const float* __restrict__ A_abslog,
                    const float* __restrict__ A_phase,
                    const float* __restrict__ C,
                    float* __restrict__ out)
{
    __shared__ float s_al[N], s_ph[N];   // dtA = al + i*ph
    __shared__ float s_Ar[N], s_Ai[N];   // A = exp(dtA)
    __shared__ float s_Cr[N], s_Ci[N];   // C' = Cc*(A-1)/dtA

    const int h     = blockIdx.x / SPLIT;
    const int lbase = (blockIdx.x % SPLIT) * LCHUNK;
    const int tid   = threadIdx.x;

    if (tid < N) {
        const float al = A_abslog[h * N + tid];
        const float ph = A_phase [h * N + tid];
        float sp, cp;
        sincosf(ph, &sp, &cp);
        const float m  = expf(al);
        const float Ar = m * cp;
        const float Ai = m * sp;
        // g = (A-1)/dtA
        const float nr    = Ar - 1.0f, ni = Ai;
        const float inv   = 1.0f / (al * al + ph * ph);
        const float gr    = (nr * al + ni * ph) * inv;
        const float gi    = (ni * al - nr * ph) * inv;
        const float cre   = C[(h * N + tid) * 2 + 0];
        const float cim   = C[(h * N + tid) * 2 + 1];
        s_al[tid] = al;  s_ph[tid] = ph;
        s_Ar[tid] = Ar;  s_Ai[tid] = Ai;
        s_Cr[tid] = cre * gr - cim * gi;
        s_Ci[tid] = cre * gi + cim * gr;
    }
    __syncthreads();

    const int l0 = lbase + tid * LPT;

    float acc[LPT];
#pragma unroll
    for (int j = 0; j < LPT; ++j) acc[j] = 0.0f;

    for (int n = 0; n < N; ++n) {
        const float al = s_al[n];
        const float ph = s_ph[n];

        // w = A^l0 = exp(al*l0) * (cos(ph*l0) + i*sin(ph*l0))
        // angle reduced in double: ph*l0 reaches ~1.3e4; f32 product alone
        // carries ~1e-3 rad error.
        const float  mag  = expf(al * (float)l0);
        const double tred = fmod((double)ph * (double)l0,
                                 6.2831853071795864769);
        float sth, cth;
        sincosf((float)tred, &sth, &cth);
        const float wr = mag * cth;
        const float wi = mag * sth;

        // x = C' * w, then recur x *= A for successive l
        const float pr = s_Cr[n], pi = s_Ci[n];
        float xr = pr * wr - pi * wi;
        float xi = pr * wi + pi * wr;

        const float Ar = s_Ar[n], Ai = s_Ai[n];
#pragma unroll
        for (int j = 0; j < LPT; ++j) {
            acc[j] += xr;
            const float tr = xr * Ar - xi * Ai;
            xi = xr * Ai + xi * Ar;
            xr = tr;
        }
    }

    // coalesced vector store: each thread owns LPT consecutive l
    float4* o = reinterpret_cast<float4*>(out + h * L + l0);
#pragma unroll
    for (int j = 0; j < LPT / 4; ++j) {
        float4 v;
        v.x = 2.0f * acc[4 * j + 0];
        v.y = 2.0f * acc[4 * j + 1];
        v.z = 2.0f * acc[4 * j + 2];
        v.w = 2.0f * acc[4 * j + 3];
        o[j] = v;
    }
}

extern "C" void kernel_launch(void* const* d_in, const int* in_sizes, int n_in,
                              void* d_out, int out_size, void* d_ws, size_t ws_size,
                              hipStream_t stream)
{
    const float* A_abslog = (const float*)d_in[0];
    const float* A_phase  = (const float*)d_in[1];
    const float* C        = (const float*)d_in[2];
    // d_in[3] is L (=4096), fixed by the harness shape; hardcoded.
    float* out = (float*)d_out;

    sskdiag_kernel<<<H * SPLIT, BLK, 0, stream>>>(A_abslog, A_phase, C, out);
}

// Round 2
// 20.934 us; speedup vs baseline: 1.9267x; 1.9267x over previous
//
#include <hip/hip_runtime.h>
#include <math.h>

// SSKernelDiag: out[0,h,l] = 2*Re( sum_n C'[h,n] * A[h,n]^l )
//   A  = exp(al + i*ph),  C' = (C0 + i*C1)*(A-1)/(al + i*ph)
// H=256, N=64, L=4096, CH=1.
//
// Power factorization: l = lbase + 512*w + 8*r + j  (w=wave, r=lane, j=0..7)
//   A^l = [A^lbase * (A^512)^w]  *  (A^8)^r  *  A^j
//          `-- folded into C' --'    `-tab1-'   `-6-flop recurrence-'
// Main loop is pure FMA; all transcendentals are in one-time table setup.

constexpr int H = 256;
constexpr int N = 64;
constexpr int L = 4096;

constexpr int SPLIT  = 2;            // l-range splits per head
constexpr int BLK    = 256;          // 4 waves
constexpr int WAVES  = BLK / 64;
constexpr int LCHUNK = L / SPLIT;    // 2048 l per block
constexpr int LPT    = 8;            // l per thread (recurrence length)
constexpr int WCHUNK = 64 * LPT;     // 512 l per wave

__device__ __forceinline__ float reduce_angle(float ph, int k)
{
    // ph*k up to ~1.3e4 rad; reduce in double (manual, avoids fmod call)
    double t = (double)ph * (double)k;
    double m = t * 0.15915494309189535;   // 1/(2*pi)
    double f = m - floor(m);
    return (float)(f * 6.283185307179586);
}

__global__ __launch_bounds__(BLK)
void sskdiag_kernel(const float* __restrict__ A_abslog,
                    const float* __restrict__ A_phase,
                    const float* __restrict__ C,
                    float* __restrict__ out)
{
    __shared__ float  s_al[N], s_ph[N];
    __shared__ float2 s_A[N];            // A
    __shared__ float2 s_Cp[N];           // C'
    __shared__ float2 s_tab1[N][64];     // (A^8)^r
    __shared__ float4 s_mix[N][WAVES];   // {Re/Im of C'*A^(lbase+512w), Ar, Ai}

    const int h     = blockIdx.x / SPLIT;
    const int lbase = (blockIdx.x % SPLIT) * LCHUNK;
    const int tid   = threadIdx.x;

    // ---- phase A: per-n scalars (lanes 0..63) ----
    if (tid < N) {
        const float al = A_abslog[h * N + tid];
        const float ph = A_phase [h * N + tid];
        float sp, cp;
        sincosf(ph, &sp, &cp);
        const float m  = expf(al);
        const float Ar = m * cp;
        const float Ai = m * sp;
        const float nr  = Ar - 1.0f, ni = Ai;
        const float inv = 1.0f / (al * al + ph * ph);
        const float gr  = (nr * al + ni * ph) * inv;
        const float gi  = (ni * al - nr * ph) * inv;
        const float cre = C[(h * N + tid) * 2 + 0];
        const float cim = C[(h * N + tid) * 2 + 1];
        s_al[tid] = al;  s_ph[tid] = ph;
        s_A [tid] = make_float2(Ar, Ai);
        s_Cp[tid] = make_float2(cre * gr - cim * gi, cre * gi + cim * gr);
    }
    __syncthreads();

    // ---- phase B: tables (all 256 threads) ----
    // tab1[n][r] = A_n^(8r): 4096 entries, 16 per thread
    #pragma unroll 4
    for (int k = 0; k < (N * 64) / BLK; ++k) {
        const int e = tid + BLK * k;
        const int n = e >> 6, r = e & 63;
        const float al = s_al[n], ph = s_ph[n];
        const float mag = expf(al * (float)(8 * r));
        float s, c;
        sincosf(reduce_angle(ph, 8 * r), &s, &c);
        s_tab1[n][r] = make_float2(mag * c, mag * s);
    }
    // mix[n][w] = {C'_n * A_n^(lbase+512w), A_n}: 256 entries, 1 per thread
    {
        const int n = tid >> 2, w = tid & (WAVES - 1);
        const int p = lbase + WCHUNK * w;
        const float al = s_al[n], ph = s_ph[n];
        const float mag = expf(al * (float)p);
        float s, c;
        sincosf(reduce_angle(ph, p), &s, &c);
        const float wr = mag * c, wi = mag * s;
        const float2 cp = s_Cp[n];
        const float2 Av = s_A[n];
        s_mix[n][w] = make_float4(cp.x * wr - cp.y * wi,
                                  cp.x * wi + cp.y * wr,
                                  Av.x, Av.y);
    }
    __syncthreads();

    // ---- phase C: pure-FMA main loop ----
    const int w    = tid >> 6;
    const int lane = tid & 63;
    const int l0   = lbase + w * WCHUNK + lane * LPT;

    float acc[LPT];
    #pragma unroll
    for (int j = 0; j < LPT; ++j) acc[j] = 0.0f;

    #pragma unroll 8
    for (int n = 0; n < N; ++n) {
        const float4 m4 = s_mix[n][w];     // wave-uniform b128 broadcast
        const float2 t1 = s_tab1[n][lane]; // per-lane b64
        float xr = m4.x * t1.x - m4.y * t1.y;
        float xi = m4.x * t1.y + m4.y * t1.x;
        #pragma unroll
        for (int j = 0; j < LPT; ++j) {
            acc[j] += xr;
            const float tr = xr * m4.z - xi * m4.w;
            xi = xr * m4.w + xi * m4.z;
            xr = tr;
        }
    }

    // coalesced-ish vector store: thread owns LPT consecutive l
    float4* o = reinterpret_cast<float4*>(out + h * L + l0);
    #pragma unroll
    for (int j = 0; j < LPT / 4; ++j) {
        float4 v;
        v.x = 2.0f * acc[4 * j + 0];
        v.y = 2.0f * acc[4 * j + 1];
        v.z = 2.0f * acc[4 * j + 2];
        v.w = 2.0f * acc[4 * j + 3];
        o[j] = v;
    }
}

extern "C" void kernel_launch(void* const* d_in, const int* in_sizes, int n_in,
                              void* d_out, int out_size, void* d_ws, size_t ws_size,
                              hipStream_t stream)
{
    const float* A_abslog = (const float*)d_in[0];
    const float* A_phase  = (const float*)d_in[1];
    const float* C        = (const float*)d_in[2];
    float* out = (float*)d_out;

    sskdiag_kernel<<<H * SPLIT, BLK, 0, stream>>>(A_abslog, A_phase, C, out);
}

// Round 3
// 18.620 us; speedup vs baseline: 2.1662x; 1.1243x over previous
//
#include <hip/hip_runtime.h>
#include <math.h>

// SSKernelDiag: out[0,h,l] = 2*Re( sum_n C'[h,n] * A[h,n]^l )
//   A  = exp(al + i*ph),  C' = (C0 + i*C1)*(A-1)/(al + i*ph)
// H=256, N=64, L=4096, CH=1.
//
// Decomposition: l = lbase + 256*w + 4*lane + j,  j in [0,4)
//   seed:  x = [C'*A^(lbase+256w)] * A^(4*lane)    (P from regs, tab from LDS)
//   only Re needed -> 2nd-order real recurrence r_{j+1} = 2Ar*r_j - |A|^2*r_{j-1}
//   r0 = Re(T*P), r1 = Re(T*Q) with Q = P*A  (4 FMA seed, no Im needed)
// Per-n wave-uniform scalars {Pr,-Pi,Qr,-Qi,2Ar,-|A|^2} live one-n-per-lane in
// registers and are broadcast with v_readlane (SGPR result -> 1-SGPR operand ok).

constexpr int H = 256;
constexpr int N = 64;
constexpr int L = 4096;

constexpr int SPLIT  = 4;            // l-range splits per head
constexpr int BLK    = 256;          // 4 waves
constexpr int WAVES  = 4;
constexpr int LCHUNK = L / SPLIT;    // 1024 l per block
constexpr int LPT    = 4;            // l per thread
constexpr int WCHUNK = 64 * LPT;     // 256 l per wave

__device__ __forceinline__ float rlanef(float v, int l)
{
    return __int_as_float(__builtin_amdgcn_readlane(__float_as_int(v), l));
}

// fractional revolutions of ph*k (k up to 4095 -> need double to keep frac)
__device__ __forceinline__ float rev_frac(float ph, int k)
{
    double m = (double)ph * (double)k * 0.15915494309189535; // /(2*pi)
    return (float)(m - floor(m));
}

__global__ __launch_bounds__(BLK, 4)
void sskdiag_kernel(const float* __restrict__ A_abslog,
                    const float* __restrict__ A_phase,
                    const float* __restrict__ C,
                    float* __restrict__ out)
{
    __shared__ float  s_al[N], s_ph[N];
    __shared__ float2 s_A[N], s_Cp[N];
    __shared__ float2 s_tab[N][64];       // A^(4r)
    __shared__ float4 s_mixPQ[WAVES][N];  // {Pr, -Pi, Qr, -Qi}
    __shared__ float2 s_cons[N];          // {2Ar, -|A|^2}

    const int h     = blockIdx.x >> 2;
    const int lbase = (blockIdx.x & 3) * LCHUNK;
    const int tid   = threadIdx.x;

    // ---- per-n scalars (lanes 0..63) ----
    if (tid < N) {
        const float al = A_abslog[h * N + tid];
        const float ph = A_phase [h * N + tid];
        float f = ph * 0.15915494309189535f;
        f = f - floorf(f);                       // revolutions in [0,1)
        const float sp = __builtin_amdgcn_sinf(f);
        const float cp = __builtin_amdgcn_cosf(f);
        const float m  = __expf(al);
        const float Ar = m * cp;
        const float Ai = m * sp;
        const float nr  = Ar - 1.0f, ni = Ai;
        const float inv = 1.0f / (al * al + ph * ph);
        const float gr  = (nr * al + ni * ph) * inv;
        const float gi  = (ni * al - nr * ph) * inv;
        const float cre = C[(h * N + tid) * 2 + 0];
        const float cim = C[(h * N + tid) * 2 + 1];
        s_al[tid] = al;  s_ph[tid] = ph;
        s_A [tid] = make_float2(Ar, Ai);
        s_Cp[tid] = make_float2(cre * gr - cim * gi, cre * gi + cim * gr);
        s_cons[tid] = make_float2(Ar + Ar, -__expf(al + al)); // |A|^2 = e^{2al}
    }
    __syncthreads();

    // ---- tab[n][r] = A_n^(4r) : 4096 entries, 16 per thread ----
    #pragma unroll
    for (int k = 0; k < (N * 64) / BLK; ++k) {
        const int e = tid + BLK * k;
        const int n = e >> 6, r = e & 63;
        const float al = s_al[n], ph = s_ph[n];
        const int   p  = 4 * r;
        const float mag = __expf(al * (float)p);
        const float f   = rev_frac(ph, p);
        s_tab[n][r] = make_float2(mag * __builtin_amdgcn_cosf(f),
                                  mag * __builtin_amdgcn_sinf(f));
    }
    // ---- mixPQ[w][n]: P = C'*A^(lbase+256w), Q = P*A  (1 entry/thread) ----
    {
        const int w = tid >> 6, n = tid & 63;
        const int p = lbase + WCHUNK * w;
        const float al = s_al[n], ph = s_ph[n];
        const float mag = __expf(al * (float)p);
        const float f   = rev_frac(ph, p);
        const float er  = mag * __builtin_amdgcn_cosf(f);
        const float ei  = mag * __builtin_amdgcn_sinf(f);
        const float2 cp = s_Cp[n];
        const float Pr  = cp.x * er - cp.y * ei;
        const float Pi  = cp.x * ei + cp.y * er;
        const float2 Av = s_A[n];
        const float Qr  = Pr * Av.x - Pi * Av.y;
        const float Qi  = Pr * Av.y + Pi * Av.x;
        s_mixPQ[w][n] = make_float4(Pr, -Pi, Qr, -Qi);
    }
    __syncthreads();

    // ---- main loop ----
    const int w    = tid >> 6;
    const int lane = tid & 63;

    // one n per lane, broadcast via readlane in the loop
    const float4 slot = s_mixPQ[w][lane];
    const float2 cc   = s_cons[lane];

    float a0 = 0.f, a1 = 0.f, a2 = 0.f, a3 = 0.f;

    #pragma unroll 8
    for (int n = 0; n < N; ++n) {
        const float2 T  = s_tab[n][lane];          // per-lane b64 (DS pipe)
        const float Pr  = rlanef(slot.x, n);       // SGPR broadcasts
        const float mPi = rlanef(slot.y, n);
        const float Qr  = rlanef(slot.z, n);
        const float mQi = rlanef(slot.w, n);
        const float c1  = rlanef(cc.x, n);         // 2Ar
        const float c2  = rlanef(cc.y, n);         // -|A|^2

        float r0 = fmaf(T.y, mPi, T.x * Pr);       // Re(T*P)
        float r1 = fmaf(T.y, mQi, T.x * Qr);       // Re(T*P*A)
        a0 += r0;
        a1 += r1;
        const float r2 = fmaf(c1, r1, c2 * r0);
        a2 += r2;
        const float r3 = fmaf(c1, r2, c2 * r1);
        a3 += r3;
    }

    // one float4 store per thread, lane-consecutive -> perfectly coalesced
    float4 v;
    v.x = 2.0f * a0;  v.y = 2.0f * a1;
    v.z = 2.0f * a2;  v.w = 2.0f * a3;
    *reinterpret_cast<float4*>(out + h * L + lbase + w * WCHUNK + lane * LPT) = v;
}

extern "C" void kernel_launch(void* const* d_in, const int* in_sizes, int n_in,
                              void* d_out, int out_size, void* d_ws, size_t ws_size,
                              hipStream_t stream)
{
    const float* A_abslog = (const float*)d_in[0];
    const float* A_phase  = (const float*)d_in[1];
    const float* C        = (const float*)d_in[2];
    float* out = (float*)d_out;

    sskdiag_kernel<<<H * SPLIT, BLK, 0, stream>>>(A_abslog, A_phase, C, out);
}

// Round 4
// 15.905 us; speedup vs baseline: 2.5360x; 1.1707x over previous
//
#include <hip/hip_runtime.h>
#include <math.h>

// SSKernelDiag: out[0,h,l] = 2*Re( sum_n C'[h,n] * A[h,n]^l )
//   A  = exp(al + i*ph),  C' = (C0 + i*C1)*(A-1)/(al + i*ph)
// H=256, N=64, L=4096, CH=1.
//
// Decomposition: l = lbase + 256*w + 4*lane + j,  j in [0,4)
//   seed x = [C'*A^(lbase+256w)] * A^(4*lane);  only Re needed ->
//   2nd-order real recurrence r_{j+1} = 2Ar*r_j - |A|^2*r_{j-1}
// Per-n wave-uniform constants come from LDS broadcast reads (b128/b64,
// same-address across the wave -> no conflicts, DS pipe co-issues with VALU).
// (Round-3's v_readlane broadcast created 384 SGPR-writing VALU ops/thread.)

constexpr int H = 256;
constexpr int N = 64;
constexpr int L = 4096;

constexpr int SPLIT  = 4;            // l-range splits per head
constexpr int BLK    = 256;          // 4 waves
constexpr int WAVES  = 4;
constexpr int LCHUNK = L / SPLIT;    // 1024 l per block
constexpr int LPT    = 4;            // l per thread
constexpr int WCHUNK = 64 * LPT;     // 256 l per wave

// fractional revolutions of ph*k (k up to 4095 -> double to keep the frac bits)
__device__ __forceinline__ float rev_frac(float ph, int k)
{
    double m = (double)ph * (double)k * 0.15915494309189535; // /(2*pi)
    return (float)(m - floor(m));
}

__global__ __launch_bounds__(BLK, 4)
void sskdiag_kernel(const float* __restrict__ A_abslog,
                    const float* __restrict__ A_phase,
                    const float* __restrict__ C,
                    float* __restrict__ out)
{
    __shared__ float  s_al[N], s_ph[N];
    __shared__ float2 s_A[N], s_Cp[N];
    __shared__ float2 s_tab[N][64];     // A^(4r), per-lane b64
    __shared__ float4 s_pq[WAVES][N];   // {Pr, -Pi, Qr, -Qi}, wave-uniform b128
    __shared__ float2 s_cc[N];          // {2Ar, -|A|^2},     wave-uniform b64

    const int h     = blockIdx.x >> 2;
    const int lbase = (blockIdx.x & 3) * LCHUNK;
    const int tid   = threadIdx.x;

    // ---- per-n scalars (lanes 0..63) ----
    if (tid < N) {
        const float al = A_abslog[h * N + tid];
        const float ph = A_phase [h * N + tid];
        float f = ph * 0.15915494309189535f;
        f = f - floorf(f);                       // revolutions in [0,1)
        const float sp = __builtin_amdgcn_sinf(f);
        const float cp = __builtin_amdgcn_cosf(f);
        const float m  = __expf(al);
        const float Ar = m * cp;
        const float Ai = m * sp;
        const float nr  = Ar - 1.0f, ni = Ai;
        const float inv = 1.0f / (al * al + ph * ph);
        const float gr  = (nr * al + ni * ph) * inv;
        const float gi  = (ni * al - nr * ph) * inv;
        const float cre = C[(h * N + tid) * 2 + 0];
        const float cim = C[(h * N + tid) * 2 + 1];
        s_al[tid] = al;  s_ph[tid] = ph;
        s_A [tid] = make_float2(Ar, Ai);
        s_Cp[tid] = make_float2(cre * gr - cim * gi, cre * gi + cim * gr);
        s_cc[tid] = make_float2(Ar + Ar, -__expf(al + al)); // |A|^2 = e^{2al}
    }
    __syncthreads();

    // ---- tab[n][r] = A_n^(4r) : 4096 entries, 16 per thread ----
    #pragma unroll
    for (int k = 0; k < (N * 64) / BLK; ++k) {
        const int e = tid + BLK * k;
        const int n = e >> 6, r = e & 63;
        const float al = s_al[n], ph = s_ph[n];
        const int   p  = 4 * r;
        const float mag = __expf(al * (float)p);
        const float f   = rev_frac(ph, p);
        s_tab[n][r] = make_float2(mag * __builtin_amdgcn_cosf(f),
                                  mag * __builtin_amdgcn_sinf(f));
    }
    // ---- pq[w][n]: P = C'*A^(lbase+256w), Q = P*A  (1 entry/thread) ----
    {
        const int w = tid >> 6, n = tid & 63;
        const int p = lbase + WCHUNK * w;
        const float al = s_al[n], ph = s_ph[n];
        const float mag = __expf(al * (float)p);
        const float f   = rev_frac(ph, p);
        const float er  = mag * __builtin_amdgcn_cosf(f);
        const float ei  = mag * __builtin_amdgcn_sinf(f);
        const float2 cp = s_Cp[n];
        const float Pr  = cp.x * er - cp.y * ei;
        const float Pi  = cp.x * ei + cp.y * er;
        const float2 Av = s_A[n];
        const float Qr  = Pr * Av.x - Pi * Av.y;
        const float Qi  = Pr * Av.y + Pi * Av.x;
        s_pq[w][n] = make_float4(Pr, -Pi, Qr, -Qi);
    }
    __syncthreads();

    // ---- main loop: 3 DS reads + 12 VALU per n ----
    const int w    = tid >> 6;
    const int lane = tid & 63;

    float a0 = 0.f, a1 = 0.f, a2 = 0.f, a3 = 0.f;

    #pragma unroll 8
    for (int n = 0; n < N; ++n) {
        const float2 T  = s_tab[n][lane];   // per-lane b64 (2-way alias: free)
        const float4 PQ = s_pq[w][n];       // broadcast b128
        const float2 CC = s_cc[n];          // broadcast b64

        float r0 = fmaf(T.y, PQ.y, T.x * PQ.x);   // Re(T*P)
        float r1 = fmaf(T.y, PQ.w, T.x * PQ.z);   // Re(T*P*A)
        a0 += r0;
        a1 += r1;
        const float r2 = fmaf(CC.x, r1, CC.y * r0);
        a2 += r2;
        const float r3 = fmaf(CC.x, r2, CC.y * r1);
        a3 += r3;
    }

    // one float4 store per thread, lane-consecutive -> perfectly coalesced
    float4 v;
    v.x = 2.0f * a0;  v.y = 2.0f * a1;
    v.z = 2.0f * a2;  v.w = 2.0f * a3;
    *reinterpret_cast<float4*>(out + h * L + lbase + w * WCHUNK + lane * LPT) = v;
}

extern "C" void kernel_launch(void* const* d_in, const int* in_sizes, int n_in,
                              void* d_out, int out_size, void* d_ws, size_t ws_size,
                              hipStream_t stream)
{
    const float* A_abslog = (const float*)d_in[0];
    const float* A_phase  = (const float*)d_in[1];
    const float* C        = (const float*)d_in[2];
    float* out = (float*)d_out;

    sskdiag_kernel<<<H * SPLIT, BLK, 0, stream>>>(A_abslog, A_phase, C, out);
}

// Round 5
// 15.472 us; speedup vs baseline: 2.6069x; 1.0280x over previous
//
#include <hip/hip_runtime.h>
#include <math.h>

// SSKernelDiag: out[0,h,l] = 2*Re( sum_n C'[h,n] * A[h,n]^l )
//   A  = exp(al + i*ph),  C' = (C0 + i*C1)*(A-1)/(al + i*ph)
// H=256, N=64, L=4096, CH=1.
//
// l = lbase + 256*w + 4*lane + j, j in [0,4).
// seed x = [C'*A^(lbase+256w)] * A^(4*lane); Re-only 2nd-order recurrence
//   r_{j+1} = 2Ar*r_j - |A|^2*r_{j-1}.
// Main loop processes TWO n per iteration with packed f32x2 math
// (v_pk_fma_f32: gfx950 f32 peak requires packed ops). Table stored
// pre-packed over n-pairs; P/Q/C constants pre-packed as float4 pairs.
// Setup trig is all-f32 (one f64 frac per n in phase A only) + HW sin/cos
// in revolutions.

typedef float f32x2 __attribute__((ext_vector_type(2)));

constexpr int H = 256;
constexpr int N = 64;
constexpr int L = 4096;

constexpr int SPLIT  = 4;
constexpr int BLK    = 256;          // 4 waves
constexpr int WAVES  = 4;
constexpr int LCHUNK = L / SPLIT;    // 1024 l per block
constexpr int LPT    = 4;
constexpr int WCHUNK = 64 * LPT;     // 256 l per wave
constexpr int NP     = N / 2;        // 32 n-pairs

__global__ __launch_bounds__(BLK, 4)
void sskdiag_kernel(const float* __restrict__ A_abslog,
                    const float* __restrict__ A_phase,
                    const float* __restrict__ C,
                    float* __restrict__ out)
{
    __shared__ f32x2 s_tabx[NP][64];   // {Tx[2k], Tx[2k+1]} per lane r
    __shared__ f32x2 s_taby[NP][64];   // {Ty[2k], Ty[2k+1]}
    __shared__ float4 s_P[WAVES][NP];  // {Pr0,Pr1,-Pi0,-Pi1}
    __shared__ float4 s_Q[WAVES][NP];  // {Qr0,Qr1,-Qi0,-Qi1}
    __shared__ float4 s_Cc[NP];        // {c1_0,c1_1,c2_0,c2_1}; c1=2Ar, c2=-|A|^2
    __shared__ float  s_alf[N], s_phrev[N];
    __shared__ float2 s_A[N], s_Cp[N];

    const int h     = blockIdx.x >> 2;
    const int lbase = (blockIdx.x & 3) * LCHUNK;
    const int tid   = threadIdx.x;
    const int w     = tid >> 6;
    const int lane  = tid & 63;

    // ---- phase A: per-n scalars (lanes 0..63 of wave 0..3 -> tid<64) ----
    if (tid < N) {
        const float al = A_abslog[h * N + tid];
        const float ph = A_phase [h * N + tid];
        const double md = (double)ph * 0.15915494309189535;  // /(2*pi)
        const float phrev = (float)(md - floor(md));         // frac revolutions
        const float sp = __builtin_amdgcn_sinf(phrev);       // HW: revolutions
        const float cp = __builtin_amdgcn_cosf(phrev);
        const float m  = __expf(al);
        const float Ar = m * cp;
        const float Ai = m * sp;
        const float nr  = Ar - 1.0f, ni = Ai;
        const float inv = 1.0f / (al * al + ph * ph);
        const float gr  = (nr * al + ni * ph) * inv;
        const float gi  = (ni * al - nr * ph) * inv;
        const float cre = C[(h * N + tid) * 2 + 0];
        const float cim = C[(h * N + tid) * 2 + 1];
        s_alf[tid]   = al;
        s_phrev[tid] = phrev;
        s_A [tid] = make_float2(Ar, Ai);
        s_Cp[tid] = make_float2(cre * gr - cim * gi, cre * gi + cim * gr);
        float* pc = (float*)&s_Cc[tid >> 1];
        pc[tid & 1]       = Ar + Ar;           // c1
        pc[2 + (tid & 1)] = -__expf(al + al);  // c2 = -|A|^2
    }
    __syncthreads();

    // ---- tab[n][r] = A_n^(4r), packed over n-pairs ----
    // entry e = tid + 256k -> n = w + 4k (wave-uniform), r = lane
    #pragma unroll
    for (int k = 0; k < 16; ++k) {
        const int n = w + 4 * k;
        const float al    = s_alf[n];
        const float phrev = s_phrev[n];
        const float kf  = (float)(4 * lane);
        const float t   = phrev * kf;
        const float f   = t - floorf(t);
        const float mag = __expf(al * kf);
        const float tx  = mag * __builtin_amdgcn_cosf(f);
        const float ty  = mag * __builtin_amdgcn_sinf(f);
        ((float*)&s_tabx[n >> 1][lane])[n & 1] = tx;
        ((float*)&s_taby[n >> 1][lane])[n & 1] = ty;
    }

    // ---- P = C'*A^(lbase+256w), Q = P*A : one entry per thread ----
    {
        const int n = lane;
        const int p = lbase + WCHUNK * w;
        const float al    = s_alf[n];
        const float phrev = s_phrev[n];
        const float pf  = (float)p;
        const float t   = phrev * pf;
        const float f   = t - floorf(t);
        const float mag = __expf(al * pf);
        const float er  = mag * __builtin_amdgcn_cosf(f);
        const float ei  = mag * __builtin_amdgcn_sinf(f);
        const float2 cp = s_Cp[n];
        const float Pr  = cp.x * er - cp.y * ei;
        const float Pi  = cp.x * ei + cp.y * er;
        const float2 Av = s_A[n];
        const float Qr  = Pr * Av.x - Pi * Av.y;
        const float Qi  = Pr * Av.y + Pi * Av.x;
        float* pP = (float*)&s_P[w][n >> 1];
        float* pQ = (float*)&s_Q[w][n >> 1];
        pP[n & 1]       = Pr;
        pP[2 + (n & 1)] = -Pi;
        pQ[n & 1]       = Qr;
        pQ[2 + (n & 1)] = -Qi;
    }
    __syncthreads();

    // ---- main loop: 32 packed n-pair iterations ----
    f32x2 a0 = {0.f, 0.f}, a1 = {0.f, 0.f}, a2 = {0.f, 0.f}, a3 = {0.f, 0.f};

    #pragma unroll 8
    for (int k = 0; k < NP; ++k) {
        const f32x2 TX = s_tabx[k][lane];   // per-lane b64, 2 lanes/bank: free
        const f32x2 TY = s_taby[k][lane];
        const float4 P  = s_P[w][k];        // wave-uniform broadcasts
        const float4 Q  = s_Q[w][k];
        const float4 Cc = s_Cc[k];
        const f32x2 PR = {P.x,  P.y},  PI = {P.z,  P.w};
        const f32x2 QR = {Q.x,  Q.y},  QI = {Q.z,  Q.w};
        const f32x2 C1 = {Cc.x, Cc.y}, C2 = {Cc.z, Cc.w};

        f32x2 r0 = TX * PR + TY * PI;       // Re(T*P)   (packed mul+fma)
        f32x2 r1 = TX * QR + TY * QI;       // Re(T*P*A)
        a0 += r0;
        a1 += r1;
        const f32x2 r2 = C1 * r1 + C2 * r0;
        a2 += r2;
        const f32x2 r3 = C1 * r2 + C2 * r1;
        a3 += r3;
    }

    // horizontal add of the two n-halves; one coalesced float4 store
    float4 v;
    v.x = 2.0f * (a0.x + a0.y);
    v.y = 2.0f * (a1.x + a1.y);
    v.z = 2.0f * (a2.x + a2.y);
    v.w = 2.0f * (a3.x + a3.y);
    *reinterpret_cast<float4*>(out + h * L + lbase + w * WCHUNK + lane * LPT) = v;
}

extern "C" void kernel_launch(void* const* d_in, const int* in_sizes, int n_in,
                              void* d_out, int out_size, void* d_ws, size_t ws_size,
                              hipStream_t stream)
{
    const float* A_abslog = (const float*)d_in[0];
    const float* A_phase  = (const float*)d_in[1];
    const float* C        = (const float*)d_in[2];
    float* out = (float*)d_out;

    sskdiag_kernel<<<H * SPLIT, BLK, 0, stream>>>(A_abslog, A_phase, C, out);
}

// Round 6
// 11.575 us; speedup vs baseline: 3.4845x; 1.3366x over previous
//
#include <hip/hip_runtime.h>
#include <math.h>

// SSKernelDiag: out[0,h,l] = 2*Re( sum_n C'[h,n] * A[h,n]^l )
//   A  = exp(al + i*ph),  C' = (C0 + i*C1)*(A-1)/(al + i*ph)
// H=256, N=64, L=4096, CH=1.
//
// Round-6 restructure: the DS pipe (1/CU) was the bottleneck (round 4->5
// packed-VALU halving changed nothing). New layout:
//   - n split across the 4 waves (16 n = 8 pairs each); all waves cover the
//     SAME 1024-l window; cross-wave reduce at the end via padded LDS.
//   - l = lbase + 16*lane + j, j in [0,16): per-lane Vandermonde factor
//     T = A^(16*lane) computed in REGISTERS via HW exp/sin/cos (TRANS pipe),
//     no LDS table.
//   - per n-pair the main loop does only 3 broadcast b128 reads (P, Q=P*A,
//     {2Ar, -|A|^2}) amortized over 16 l, + 48 packed f32x2 ops.
//   - Re-only 2nd-order recurrence r_{j+1} = 2Ar*r_j - |A|^2*r_{j-1}.

typedef float f32x2 __attribute__((ext_vector_type(2)));

constexpr int H = 256;
constexpr int N = 64;
constexpr int L = 4096;

constexpr int BLK   = 256;
constexpr int WAVES = 4;
constexpr int NPW   = N / WAVES;     // 16 n per wave
constexpr int PPW   = NPW / 2;       // 8 pairs per wave
constexpr int LPT   = 16;            // l per lane (recurrence chain length)
constexpr int LBLK  = 64 * LPT;      // 1024 l per block
constexpr int NP    = N / 2;         // 32 pairs
constexpr int RPAD  = LPT + 1;       // 17: stride-17 rows -> 2-way banks (free)

__global__ __launch_bounds__(BLK, 4)
void sskdiag_kernel(const float* __restrict__ A_abslog,
                    const float* __restrict__ A_phase,
                    const float* __restrict__ C,
                    float* __restrict__ out)
{
    __shared__ float4 s_P[NP];     // {Pr0,Pr1,-Pi0,-Pi1},  P = C'*A^lbase
    __shared__ float4 s_Q[NP];     // {Qr0,Qr1,-Qi0,-Qi1},  Q = P*A
    __shared__ float4 s_CC[NP];    // {c1_0,c1_1,c2_0,c2_1}; c1=2Ar, c2=-|A|^2
    __shared__ float4 s_alph[NP];  // {al0,al1,phrev0,phrev1}
    __shared__ float  s_red[WAVES][64][RPAD];

    const int h     = blockIdx.x >> 2;
    const int lbase = (blockIdx.x & 3) * LBLK;
    const int tid   = threadIdx.x;
    const int w     = tid >> 6;
    const int lane  = tid & 63;

    // ---- phase A: per-n scalars (lanes 0..63) ----
    if (tid < N) {
        const int   n  = tid;
        const float al = A_abslog[h * N + n];
        const float ph = A_phase [h * N + n];
        const double inv2pi = 0.15915494309189535;
        const double md = (double)ph * inv2pi;
        const float phrev = (float)(md - floor(md));       // frac revolutions
        const float sp = __builtin_amdgcn_sinf(phrev);     // HW trig: revolutions
        const float cp = __builtin_amdgcn_cosf(phrev);
        const float m  = __expf(al);
        const float Ar = m * cp, Ai = m * sp;
        const float nr = Ar - 1.0f, ni = Ai;
        const float inv = 1.0f / (al * al + ph * ph);
        const float gr = (nr * al + ni * ph) * inv;
        const float gi = (ni * al - nr * ph) * inv;
        const float cre = C[(h * N + n) * 2 + 0];
        const float cim = C[(h * N + n) * 2 + 1];
        const float Cr = cre * gr - cim * gi;
        const float Ci = cre * gi + cim * gr;
        // P = C' * A^lbase  (angle of the big power in f64, once)
        const float magP = __expf(al * (float)lbase);
        const double mdl = (double)ph * (double)lbase * inv2pi;
        const float  fl  = (float)(mdl - floor(mdl));
        const float er = magP * __builtin_amdgcn_cosf(fl);
        const float ei = magP * __builtin_amdgcn_sinf(fl);
        const float Pr = Cr * er - Ci * ei;
        const float Pi = Cr * ei + Ci * er;
        const float Qr = Pr * Ar - Pi * Ai;
        const float Qi = Pr * Ai + Pi * Ar;
        const int pr = n >> 1, sl = n & 1;
        ((float*)&s_P [pr])[sl]     = Pr;
        ((float*)&s_P [pr])[2 + sl] = -Pi;
        ((float*)&s_Q [pr])[sl]     = Qr;
        ((float*)&s_Q [pr])[2 + sl] = -Qi;
        ((float*)&s_CC[pr])[sl]     = Ar + Ar;
        ((float*)&s_CC[pr])[2 + sl] = -(Ar * Ar + Ai * Ai);
        ((float*)&s_alph[pr])[sl]     = al;
        ((float*)&s_alph[pr])[2 + sl] = phrev;
    }
    __syncthreads();

    // ---- T[p] = A_n^(16*lane) in registers (HW trans, no LDS table) ----
    const float kf = (float)(LPT * lane);
    f32x2 TX[PPW], TY[PPW];
    #pragma unroll
    for (int p = 0; p < PPW; ++p) {
        const float4 ap = s_alph[PPW * w + p];      // broadcast
        const float m0 = __expf(ap.x * kf);
        const float m1 = __expf(ap.y * kf);
        float t0 = ap.z * kf; t0 -= floorf(t0);
        float t1 = ap.w * kf; t1 -= floorf(t1);
        TX[p] = (f32x2){ m0 * __builtin_amdgcn_cosf(t0),
                         m1 * __builtin_amdgcn_cosf(t1) };
        TY[p] = (f32x2){ m0 * __builtin_amdgcn_sinf(t0),
                         m1 * __builtin_amdgcn_sinf(t1) };
    }

    // ---- main loop: 8 pairs, 3 broadcast b128 + 48 packed VALU each ----
    f32x2 acc[LPT];
    #pragma unroll
    for (int j = 0; j < LPT; ++j) acc[j] = (f32x2){0.f, 0.f};

    #pragma unroll
    for (int p = 0; p < PPW; ++p) {
        const float4 P  = s_P [PPW * w + p];
        const float4 Q  = s_Q [PPW * w + p];
        const float4 CV = s_CC[PPW * w + p];
        const f32x2 PR = {P.x, P.y},  PI = {P.z, P.w};
        const f32x2 QR = {Q.x, Q.y},  QI = {Q.z, Q.w};
        const f32x2 C1 = {CV.x, CV.y}, C2 = {CV.z, CV.w};
        f32x2 rp = TX[p] * PR + TY[p] * PI;   // Re(T*P)
        f32x2 rc = TX[p] * QR + TY[p] * QI;   // Re(T*P*A)
        acc[0] += rp;
        acc[1] += rc;
        #pragma unroll
        for (int j = 2; j < LPT; ++j) {
            const f32x2 rn = C1 * rc + C2 * rp;
            acc[j] += rn;
            rp = rc; rc = rn;
        }
    }

    // ---- per-wave partials -> LDS (stride 17: 2-way banks, free) ----
    #pragma unroll
    for (int j = 0; j < LPT; ++j)
        s_red[w][lane][j] = acc[j].x + acc[j].y;
    __syncthreads();

    // ---- cross-wave reduce + store: thread t owns l = lbase + 4t .. +3 ----
    {
        const int lp = tid >> 2;          // source lane
        const int j0 = (tid & 3) * 4;     // source j offset
        float s0 = 0.f, s1 = 0.f, s2 = 0.f, s3 = 0.f;
        #pragma unroll
        for (int ww = 0; ww < WAVES; ++ww) {
            s0 += s_red[ww][lp][j0 + 0];
            s1 += s_red[ww][lp][j0 + 1];
            s2 += s_red[ww][lp][j0 + 2];
            s3 += s_red[ww][lp][j0 + 3];
        }
        float4 v;
        v.x = 2.0f * s0;  v.y = 2.0f * s1;
        v.z = 2.0f * s2;  v.w = 2.0f * s3;
        *reinterpret_cast<float4*>(out + h * L + lbase + 4 * tid) = v;
    }
}

extern "C" void kernel_launch(void* const* d_in, const int* in_sizes, int n_in,
                              void* d_out, int out_size, void* d_ws, size_t ws_size,
                              hipStream_t stream)
{
    const float* A_abslog = (const float*)d_in[0];
    const float* A_phase  = (const float*)d_in[1];
    const float* C        = (const float*)d_in[2];
    float* out = (float*)d_out;

    sskdiag_kernel<<<H * (L / LBLK), BLK, 0, stream>>>(A_abslog, A_phase, C, out);
}